// Round 23
// baseline (100.928 us; speedup 1.0000x reference)
//
#include <hip/hip_runtime.h>
#include <math.h>

#define NB 4
#define CH 256
#define NHEADS 4
#define HC 64
#define NT 2304    // 48*48
#define NSEGS 4    // split-K segments (cross-block)
#define KSEG 576   // keys per segment
#define NSEG 9     // 64-key chunks per segment
#define NQT 18     // 128-query tiles
#define LOG2E 1.44269504f
#define THR2 11.541561f   // 8 * log2(e): defer-max threshold in log2 domain

typedef _Float16 f16;
typedef _Float16 f16x4 __attribute__((ext_vector_type(4)));
typedef _Float16 f16x8 __attribute__((ext_vector_type(8)));
typedef float f32x4 __attribute__((ext_vector_type(4)));
typedef float f32x16 __attribute__((ext_vector_type(16)));

#define MFMA16(a, b, c) __builtin_amdgcn_mfma_f32_16x16x32_f16(a, b, c, 0, 0, 0)
#define MFMA32(a, b, c) __builtin_amdgcn_mfma_f32_32x32x16_f16(a, b, c, 0, 0, 0)

__device__ __forceinline__ void gload_lds16(const void* g, void* l) {
    __builtin_amdgcn_global_load_lds(
        (const __attribute__((address_space(1))) unsigned int*)g,
        (__attribute__((address_space(3))) unsigned int*)l, 16, 0, 0);
}

__device__ __forceinline__ unsigned pkh(float a, float b) {
    auto r = __builtin_amdgcn_cvt_pkrtz(a, b);   // __fp16 ext_vector(2)
    return __builtin_bit_cast(unsigned, r);
}
__device__ __forceinline__ void swap32(unsigned& a, unsigned& b) {
    asm volatile("v_permlane32_swap_b32 %0, %1" : "+v"(a), "+v"(b));
}

// ---------------------------------------------------------------------------
// Weight f32 -> f16 pre-conversion (wk, wq, wv, wo -> W16[4][65536]).
// ---------------------------------------------------------------------------
__global__ __launch_bounds__(256) void wcvt(
    const float* __restrict__ w0, const float* __restrict__ w1,
    const float* __restrict__ w2, const float* __restrict__ w3,
    f16* __restrict__ O)
{
    const int id = blockIdx.x * 256 + threadIdx.x;   // 0..32767
    const int tsel = id >> 13;                        // 0..3
    const int off = (id & 8191) * 8;
    const float* src = tsel == 0 ? w0 : (tsel == 1 ? w1 : (tsel == 2 ? w2 : w3));
    const float4 a = *reinterpret_cast<const float4*>(src + off);
    const float4 b = *reinterpret_cast<const float4*>(src + off + 4);
    f16x8 o = {(f16)a.x, (f16)a.y, (f16)a.z, (f16)a.w,
               (f16)b.x, (f16)b.y, (f16)b.z, (f16)b.w};
    *reinterpret_cast<f16x8*>(&O[(size_t)tsel * 65536 + off]) = o;
}

// ---------------------------------------------------------------------------
// Fused K/Q/V projection v4: 32-row n-tiles (2x blocks -> 864, latency fix).
// Q is PRE-SCALED by log2(e) so attention softmax runs in exp2 domain.
// grid (72, 3, 4), block 256.  Outputs: K,Q [b][h][n][64c]; V [b][h][64c][n].
// ---------------------------------------------------------------------------
__global__ __launch_bounds__(256) void proj_qkv_v4(
    const f16* __restrict__ W16,
    const float* __restrict__ bk, const float* __restrict__ bq,
    const float* __restrict__ bv,
    const float* __restrict__ X,
    f16* __restrict__ Kt, f16* __restrict__ Qt, f16* __restrict__ Vg)
{
    __shared__ __align__(16) char SMEM[20480];
    f16 (*T)[264] = reinterpret_cast<f16(*)[264]>(SMEM);   // x-tile [32n][256c+pad]
    f16 (*Vt)[40] = reinterpret_cast<f16(*)[40]>(SMEM);    // V out  [256c][32n+pad]

    const int t = threadIdx.x, l = t & 63, w = t >> 6;
    const int lm = l & 15, lg = l >> 4;
    const int n0 = blockIdx.x * 32;
    const int sel = blockIdx.y;
    const int b = blockIdx.z;

    const f16* W = W16 + (size_t)sel * 65536;
    const float* Bi = sel == 0 ? bk : (sel == 1 ? bq : bv);

    // ---- stage x[b][0..255][n0..n0+32) transposed -> T[n][c] ------------
    {
        const int cq = t >> 3;            // 0..31
        const int nq = (t & 7) * 4;       // 0,4,...,28
#pragma unroll
        for (int p = 0; p < 8; ++p) {
            const int c = p * 32 + cq;
            const float4 v = *reinterpret_cast<const float4*>(
                &X[((size_t)b * CH + c) * NT + n0 + nq]);
            T[nq + 0][c] = (f16)v.x;
            T[nq + 1][c] = (f16)v.y;
            T[nq + 2][c] = (f16)v.z;
            T[nq + 3][c] = (f16)v.w;
        }
    }
    __syncthreads();

    f32x4 acc[4][2] = {};   // [h][nt]

#pragma unroll 2
    for (int ks = 0; ks < 8; ++ks) {
        f16x8 bf[2];
#pragma unroll
        for (int nt = 0; nt < 2; ++nt)
            bf[nt] = *reinterpret_cast<const f16x8*>(
                &T[nt * 16 + lm][ks * 32 + lg * 8]);
#pragma unroll
        for (int h = 0; h < 4; ++h) {
            const f16x8 a = *reinterpret_cast<const f16x8*>(
                &W[(size_t)(h * 64 + w * 16 + lm) * CH + ks * 32 + lg * 8]);
#pragma unroll
            for (int nt = 0; nt < 2; ++nt)
                acc[h][nt] = MFMA16(a, bf[nt], acc[h][nt]);
        }
    }

    const int c_base = w * 16 + lg * 4;
    if (sel < 2) {
        f16* Out = sel == 0 ? Kt : Qt;
        const float sc = sel == 1 ? LOG2E : 1.0f;   // Q pre-scaled for exp2
#pragma unroll
        for (int h = 0; h < 4; ++h) {
            const float4 b4 = *reinterpret_cast<const float4*>(&Bi[h * 64 + c_base]);
            const float bb[4] = {b4.x, b4.y, b4.z, b4.w};
#pragma unroll
            for (int nt = 0; nt < 2; ++nt) {
                const int n = n0 + nt * 16 + lm;
                f16x4 o = {(f16)((acc[h][nt][0] + bb[0]) * sc),
                           (f16)((acc[h][nt][1] + bb[1]) * sc),
                           (f16)((acc[h][nt][2] + bb[2]) * sc),
                           (f16)((acc[h][nt][3] + bb[3]) * sc)};
                *reinterpret_cast<f16x4*>(
                    &Out[((size_t)((b * NHEADS + h) * NT + n)) * HC + c_base]) = o;
            }
        }
    } else {
        __syncthreads();   // x-tile dead; reuse SMEM as Vt[256][40]
#pragma unroll
        for (int h = 0; h < 4; ++h)
#pragma unroll
            for (int nt = 0; nt < 2; ++nt)
#pragma unroll
                for (int r = 0; r < 4; ++r)
                    Vt[h * 64 + c_base + r][nt * 16 + lm] = (f16)acc[h][nt][r];
        __syncthreads();
#pragma unroll
        for (int p = 0; p < 4; ++p) {
            const int c  = p * 64 + (t >> 2);   // 0..255
            const int nn = (t & 3) * 8;
            const float bb = Bi[c];
            const f16x8 vv = *reinterpret_cast<const f16x8*>(&Vt[c][nn]);
            f16x8 o;
#pragma unroll
            for (int j = 0; j < 8; ++j) o[j] = (f16)((float)vv[j] + bb);
            *reinterpret_cast<f16x8*>(
                &Vg[((size_t)((b * NHEADS + (c >> 6)) * HC + (c & 63))) * NT
                    + n0 + nn]) = o;
        }
    }
}

// ---------------------------------------------------------------------------
// Flash attention PASS 1 (exp2 domain): 128-query tiles, split-K x4,
// double-buffered one-barrier-per-chunk.  Q arrives pre-scaled by log2e, so
// P = exp2(S' - m') == exp(S - m); all m/l bookkeeping in log2 domain.
// grid 1152 = (18 qt x 4 seg x 16 bh, XCD-mapped), block 256 = 4 waves x 32q.
// ---------------------------------------------------------------------------
__global__ __launch_bounds__(256) void attn_p1(
    const f16* __restrict__ Kt, const f16* __restrict__ Qt,
    const f16* __restrict__ Vg,
    f16* __restrict__ Pa, float* __restrict__ Pm, float* __restrict__ Pl)
{
    __shared__ f16 SM[2][2][4096];   // [buf][K/V][64 rows x 64c], 32 KB

    const int t = threadIdx.x, l = t & 63, w = t >> 6;
    const int col = l & 31, hi = l >> 5;

    const int bid = blockIdx.x;
    const int xcd = bid & 7, idx = bid >> 3;          // 144 per XCD
    const int second = idx >= 72 ? 1 : 0;
    const int bh = 2 * xcd + second;                  // 2 (b,h) pairs per XCD
    const int idx2 = idx - 72 * second;               // 0..71
    const int qt = idx2 >> 2, seg = idx2 & 3;
    const int b = bh >> 2, h = bh & 3;
    const int m0 = qt * 128;

    const size_t bhs = (size_t)(b * NHEADS + h);
    const f16* Kb = Kt + bhs * NT * HC;   // [n][64c]
    const f16* Qb = Qt + bhs * NT * HC;
    const f16* Vb = Vg + bhs * HC * NT;   // [c][n]

    const int srow = l >> 3, su = l & 7, sx = su ^ srow;

    const int q = m0 + w * 32 + col;
    f16x8 qf[4];
#pragma unroll
    for (int cs = 0; cs < 4; ++cs)
        qf[cs] = *reinterpret_cast<const f16x8*>(
            &Qb[(size_t)q * HC + cs * 16 + hi * 8]);

    const f32x16 Z16 = {0,0,0,0,0,0,0,0,0,0,0,0,0,0,0,0};
    f32x16 acc0 = Z16, acc1 = Z16;
    float m_run = -3.0e38f, l_run = 0.0f;

    const int kbase = seg * KSEG;

    auto stage = [&](int kc, int buf) {
        const int half = (w & 1) * 32;
        if (w < 2) {
            const char* src = (const char*)(Kb + (size_t)kc * HC);
            char* dst = (char*)&SM[buf][0][0];
#pragma unroll
            for (int g = 0; g < 4; ++g) {
                const int rb = half + g * 8;
                gload_lds16(src + (size_t)(rb + srow) * 128 + (sx << 4),
                            dst + rb * 128);
            }
        } else {
            const char* src = (const char*)Vb + (size_t)kc * 2;
            char* dst = (char*)&SM[buf][1][0];
#pragma unroll
            for (int g = 0; g < 4; ++g) {
                const int rb = half + g * 8;
                gload_lds16(src + (size_t)(rb + srow) * (NT * 2) + (sx << 4),
                            dst + rb * 128);
            }
        }
    };

    auto rd = [&](const f16* base, int row, int u) -> f16x8 {
        return *reinterpret_cast<const f16x8*>(
            base + row * 64 + ((u ^ (row & 7)) << 3));
    };

    stage(kbase, 0);
    __syncthreads();

    for (int i = 0; i < NSEG; ++i) {
        const int cur = i & 1;
        if (i + 1 < NSEG) stage(kbase + (i + 1) * 64, cur ^ 1);

        const f16* Kc = &SM[cur][0][0];
        const f16* Vc = &SM[cur][1][0];

        f32x16 s0 = Z16, s1 = Z16;
#pragma unroll
        for (int cs = 0; cs < 4; ++cs) {
            const f16x8 k0 = rd(Kc, col,      cs * 2 + hi);
            const f16x8 k1 = rd(Kc, 32 + col, cs * 2 + hi);
            s0 = MFMA32(k0, qf[cs], s0);
            s1 = MFMA32(k1, qf[cs], s1);
        }

        float m8[8];
#pragma unroll
        for (int j = 0; j < 8; ++j)
            m8[j] = fmaxf(fmaxf(s0[2 * j], s0[2 * j + 1]),
                          fmaxf(s1[2 * j], s1[2 * j + 1]));
        float cm = fmaxf(fmaxf(fmaxf(m8[0], m8[1]), fmaxf(m8[2], m8[3])),
                         fmaxf(fmaxf(m8[4], m8[5]), fmaxf(m8[6], m8[7])));
        cm = fmaxf(cm, __shfl_xor(cm, 32));
        if (!__all(cm <= m_run + THR2)) {     // defer-max (log2 domain)
            const float mN = fmaxf(m_run, cm);
            const float fac = exp2f(m_run - mN);
#pragma unroll
            for (int r = 0; r < 16; ++r) { acc0[r] *= fac; acc1[r] *= fac; }
            l_run *= fac;
            m_run = mN;
        }
        float p0[16], p1[16];
        float ps0 = 0.f, ps1 = 0.f, ps2 = 0.f, ps3 = 0.f;
#pragma unroll
        for (int r = 0; r < 4; ++r) {
            p0[r]      = exp2f(s0[r]      - m_run); ps0 += p0[r];
            p0[r + 4]  = exp2f(s0[r + 4]  - m_run); ps1 += p0[r + 4];
            p0[r + 8]  = exp2f(s0[r + 8]  - m_run); ps2 += p0[r + 8];
            p0[r + 12] = exp2f(s0[r + 12] - m_run); ps3 += p0[r + 12];
            p1[r]      = exp2f(s1[r]      - m_run); ps0 += p1[r];
            p1[r + 4]  = exp2f(s1[r + 4]  - m_run); ps1 += p1[r + 4];
            p1[r + 8]  = exp2f(s1[r + 8]  - m_run); ps2 += p1[r + 8];
            p1[r + 12] = exp2f(s1[r + 12] - m_run); ps3 += p1[r + 12];
        }
        l_run += (ps0 + ps1) + (ps2 + ps3);

        unsigned a0[8], a1[8];
#pragma unroll
        for (int j = 0; j < 8; ++j) {
            a0[j] = pkh(p0[2 * j], p0[2 * j + 1]);
            a1[j] = pkh(p1[2 * j], p1[2 * j + 1]);
        }
        swap32(a0[0], a0[2]); swap32(a0[1], a0[3]);
        swap32(a0[4], a0[6]); swap32(a0[5], a0[7]);
        swap32(a1[0], a1[2]); swap32(a1[1], a1[3]);
        swap32(a1[4], a1[6]); swap32(a1[5], a1[7]);
        union BU { unsigned u[4]; f16x8 v; };
        BU fr[4];
        fr[0].u[0] = a0[0]; fr[0].u[1] = a0[1]; fr[0].u[2] = a0[2]; fr[0].u[3] = a0[3];
        fr[1].u[0] = a0[4]; fr[1].u[1] = a0[5]; fr[1].u[2] = a0[6]; fr[1].u[3] = a0[7];
        fr[2].u[0] = a1[0]; fr[2].u[1] = a1[1]; fr[2].u[2] = a1[2]; fr[2].u[3] = a1[3];
        fr[3].u[0] = a1[4]; fr[3].u[1] = a1[5]; fr[3].u[2] = a1[6]; fr[3].u[3] = a1[7];

#pragma unroll
        for (int kk = 0; kk < 4; ++kk) {
            const f16x8 v0 = rd(Vc, col,      kk * 2 + hi);
            const f16x8 v1 = rd(Vc, 32 + col, kk * 2 + hi);
            acc0 = MFMA32(v0, fr[kk].v, acc0);
            acc1 = MFMA32(v1, fr[kk].v, acc1);
        }

        __syncthreads();   // publishes prefetch; frees buf for i+1's stage
    }

    // ---- publish normalized partials (m in log2 domain) -----------------
    const float l_full = l_run + __shfl_xor(l_run, 32);
    const float inv = 1.0f / l_full;
    const size_t pq = ((size_t)((seg * 16 + bh) * NQT + qt)) * 128 + w * 32 + col;
    if (hi == 0) { Pm[pq] = m_run; Pl[pq] = l_full; }
    f16* row = Pa + pq * 64;
#pragma unroll
    for (int rq = 0; rq < 4; ++rq) {
        const int c0 = rq * 8 + hi * 4;
        f16x4 o0 = {(f16)(acc0[rq * 4 + 0] * inv), (f16)(acc0[rq * 4 + 1] * inv),
                    (f16)(acc0[rq * 4 + 2] * inv), (f16)(acc0[rq * 4 + 3] * inv)};
        f16x4 o1 = {(f16)(acc1[rq * 4 + 0] * inv), (f16)(acc1[rq * 4 + 1] * inv),
                    (f16)(acc1[rq * 4 + 2] * inv), (f16)(acc1[rq * 4 + 3] * inv)};
        *reinterpret_cast<f16x4*>(row + c0) = o0;
        *reinterpret_cast<f16x4*>(row + 32 + c0) = o1;
    }
}

// ---------------------------------------------------------------------------
// FUSED merge + final conv1x1, 32-row tiles (2x blocks -> 288).
// grid (72, 4) = (ntile32, b), block 256.
// Phase 1: 4-way exact merge (exp2 weights) -> LDS T[32][264].
// Phase 2: GEMM over all 4 o-tiles; write Y f32 + bias.
// ---------------------------------------------------------------------------
__global__ __launch_bounds__(256) void out_fused(
    const f16* __restrict__ wo16, const float* __restrict__ bo,
    const f16* __restrict__ Pa, const float* __restrict__ Pm,
    const float* __restrict__ Pl, float* __restrict__ Y)
{
    __shared__ f16 T[32][264];   // merged attention output tile [n][c]

    const int t = threadIdx.x, l = t & 63, w = t >> 6;
    const int lm = l & 15, lg = l >> 4;
    const int n0 = blockIdx.x * 32;
    const int b = blockIdx.y;
    const int qt = n0 >> 7, ql0 = n0 & 127;

    // ---- phase 1: merge. thread t: row n = t>>3, 8 ch c8 = (t&7)*8 ------
    {
        const int n = t >> 3, c8 = (t & 7) * 8;
#pragma unroll
        for (int h = 0; h < 4; ++h) {
            const int bh = b * NHEADS + h;
            size_t ix[NSEGS];
            float m[NSEGS], c[NSEGS];
            float M = -3.0e38f;
#pragma unroll
            for (int s = 0; s < NSEGS; ++s) {
                ix[s] = ((size_t)((s * 16 + bh) * NQT + qt)) * 128 + ql0 + n;
                m[s] = Pm[ix[s]];
                M = fmaxf(M, m[s]);
            }
            float csum = 0.f;
#pragma unroll
            for (int s = 0; s < NSEGS; ++s) {
                c[s] = exp2f(m[s] - M) * Pl[ix[s]];
                csum += c[s];
            }
            const float inv = 1.0f / csum;
            float v[8] = {};
#pragma unroll
            for (int s = 0; s < NSEGS; ++s) {
                const f16x8 a = *reinterpret_cast<const f16x8*>(
                    Pa + ix[s] * 64 + c8);
#pragma unroll
                for (int j = 0; j < 8; ++j) v[j] += c[s] * (float)a[j];
            }
            f16x8 o;
#pragma unroll
            for (int j = 0; j < 8; ++j) o[j] = (f16)(v[j] * inv);
            *reinterpret_cast<f16x8*>(&T[n][h * 64 + c8]) = o;
        }
    }
    __syncthreads();

    // ---- phase 2: GEMM, all 4 o-tiles ------------------------------------
    f32x4 acc[4][2] = {};   // [h'][nt]
#pragma unroll 2
    for (int ks = 0; ks < 8; ++ks) {
        f16x8 bf[2];
#pragma unroll
        for (int nt = 0; nt < 2; ++nt)
            bf[nt] = *reinterpret_cast<const f16x8*>(
                &T[nt * 16 + lm][ks * 32 + lg * 8]);
#pragma unroll
        for (int hp = 0; hp < 4; ++hp) {
            const f16x8 a = *reinterpret_cast<const f16x8*>(
                &wo16[(size_t)(hp * 64 + w * 16 + lm) * CH + ks * 32 + lg * 8]);
#pragma unroll
            for (int nt = 0; nt < 2; ++nt)
                acc[hp][nt] = MFMA16(a, bf[nt], acc[hp][nt]);
        }
    }

    const int c_base = w * 16 + lg * 4;
#pragma unroll
    for (int hp = 0; hp < 4; ++hp) {
        const float4 b4 = *reinterpret_cast<const float4*>(&bo[hp * 64 + c_base]);
        const float bb[4] = {b4.x, b4.y, b4.z, b4.w};
#pragma unroll
        for (int nt = 0; nt < 2; ++nt) {
            const int n = n0 + nt * 16 + lm;
#pragma unroll
            for (int r = 0; r < 4; ++r)
                Y[((size_t)(b * CH + hp * 64 + c_base + r)) * NT + n] =
                    acc[hp][nt][r] + bb[r];
        }
    }
}

// ---------------------------------------------------------------------------
extern "C" void kernel_launch(void* const* d_in, const int* in_sizes, int n_in,
                              void* d_out, int out_size, void* d_ws, size_t ws_size,
                              hipStream_t stream) {
    (void)in_sizes; (void)n_in; (void)out_size; (void)ws_size;
    const float* x  = (const float*)d_in[0];
    const float* wk = (const float*)d_in[1];
    const float* bk = (const float*)d_in[2];
    const float* wq = (const float*)d_in[3];
    const float* bq = (const float*)d_in[4];
    const float* wv = (const float*)d_in[5];
    const float* bv = (const float*)d_in[6];
    const float* wo = (const float*)d_in[7];
    const float* bo = (const float*)d_in[8];
    float* out = (float*)d_out;

    const size_t SZ = (size_t)NB * NT * CH;           // 2,359,296 f16 per tensor
    f16* Kt  = (f16*)d_ws;                            // [b][h][n][c]
    f16* Qt  = Kt + SZ;                               // [b][h][n][c] (pre-scaled)
    f16* Vg  = Qt + SZ;                               // [b][h][c][n]
    f16* W16 = Vg + SZ;                               // [4][65536] f16
    f16* Pa  = W16 + 4 * 65536;                       // [4][16][18][128][64] f16
    float* Pm = (float*)(Pa + (size_t)NSEGS * 16 * NQT * 128 * 64);
    float* Pl = Pm + (size_t)NSEGS * 16 * NQT * 128;  // total ws ~34 MB

    wcvt<<<dim3(128), 256, 0, stream>>>(wk, wq, wv, wo, W16);
    proj_qkv_v4<<<dim3(72, 3, 4), 256, 0, stream>>>(
        W16, bk, bq, bv, x, Kt, Qt, Vg);
    attn_p1<<<dim3(1152), 256, 0, stream>>>(Kt, Qt, Vg, Pa, Pm, Pl);
    out_fused<<<dim3(72, 4), 256, 0, stream>>>(
        W16 + 3 * 65536, bo, Pa, Pm, Pl, out);
}

// Round 24
// 84.581 us; speedup vs baseline: 1.1933x; 1.1933x over previous
//
#include <hip/hip_runtime.h>
#include <math.h>

#define NB 4
#define CH 256
#define NHEADS 4
#define HC 64
#define NT 2304    // 48*48
#define NSEGS 4    // split-K segments (cross-block)
#define KSEG 576   // keys per segment
#define NSEG 9     // 64-key chunks per segment
#define NQT 18     // 128-query tiles
#define LOG2E 1.44269504f
#define THR2 11.541561f   // 8 * log2(e): defer-max threshold, log2 domain

typedef _Float16 f16;
typedef _Float16 f16x4 __attribute__((ext_vector_type(4)));
typedef _Float16 f16x8 __attribute__((ext_vector_type(8)));
typedef float f32x4 __attribute__((ext_vector_type(4)));
typedef float f32x16 __attribute__((ext_vector_type(16)));

#define MFMA16(a, b, c) __builtin_amdgcn_mfma_f32_16x16x32_f16(a, b, c, 0, 0, 0)
#define MFMA32(a, b, c) __builtin_amdgcn_mfma_f32_32x32x16_f16(a, b, c, 0, 0, 0)

__device__ __forceinline__ void gload_lds16(const void* g, void* l) {
    __builtin_amdgcn_global_load_lds(
        (const __attribute__((address_space(1))) unsigned int*)g,
        (__attribute__((address_space(3))) unsigned int*)l, 16, 0, 0);
}

__device__ __forceinline__ unsigned pkh(float a, float b) {
    auto r = __builtin_amdgcn_cvt_pkrtz(a, b);   // __fp16 ext_vector(2)
    return __builtin_bit_cast(unsigned, r);
}
__device__ __forceinline__ void swap32(unsigned& a, unsigned& b) {
    asm volatile("v_permlane32_swap_b32 %0, %1" : "+v"(a), "+v"(b));
}
// raw v_exp_f32: D = 2^S0 (single VOP1; Q is pre-scaled by log2e upstream)
__device__ __forceinline__ float ex2(float x) {
    float r;
    asm("v_exp_f32 %0, %1" : "=v"(r) : "v"(x));
    return r;
}

// ---------------------------------------------------------------------------
// Weight f32 -> f16 pre-conversion (wk, wq, wv, wo -> W16[4][65536]).
// ---------------------------------------------------------------------------
__global__ __launch_bounds__(256) void wcvt(
    const float* __restrict__ w0, const float* __restrict__ w1,
    const float* __restrict__ w2, const float* __restrict__ w3,
    f16* __restrict__ O)
{
    const int id = blockIdx.x * 256 + threadIdx.x;   // 0..32767
    const int tsel = id >> 13;                        // 0..3
    const int off = (id & 8191) * 8;
    const float* src = tsel == 0 ? w0 : (tsel == 1 ? w1 : (tsel == 2 ? w2 : w3));
    const float4 a = *reinterpret_cast<const float4*>(src + off);
    const float4 b = *reinterpret_cast<const float4*>(src + off + 4);
    f16x8 o = {(f16)a.x, (f16)a.y, (f16)a.z, (f16)a.w,
               (f16)b.x, (f16)b.y, (f16)b.z, (f16)b.w};
    *reinterpret_cast<f16x8*>(&O[(size_t)tsel * 65536 + off]) = o;
}

// ---------------------------------------------------------------------------
// Fused K/Q/V projection v3 (R22's 64-row version) + Q pre-scale by log2e.
// grid (36, 3, 4), block 256.
// ---------------------------------------------------------------------------
__global__ __launch_bounds__(256) void proj_qkv_v3(
    const f16* __restrict__ W16,
    const float* __restrict__ bk, const float* __restrict__ bq,
    const float* __restrict__ bv,
    const float* __restrict__ X,
    f16* __restrict__ Kt, f16* __restrict__ Qt, f16* __restrict__ Vg)
{
    __shared__ __align__(16) char SMEM[40960];
    f16 (*T)[264]  = reinterpret_cast<f16(*)[264]>(SMEM);   // x-tile [64n][256c+pad]
    f16 (*Vt)[80]  = reinterpret_cast<f16(*)[80]>(SMEM);    // V out  [256c][64n+pad]

    const int t = threadIdx.x, l = t & 63, w = t >> 6;
    const int lm = l & 15, lg = l >> 4;
    const int n0 = blockIdx.x * 64;
    const int sel = blockIdx.y;
    const int b = blockIdx.z;

    const f16* W = W16 + (size_t)sel * 65536;
    const float* Bi = sel == 0 ? bk : (sel == 1 ? bq : bv);

    {
        const int cq = t >> 4;
        const int nq = (t & 15) * 4;
#pragma unroll
        for (int p = 0; p < 16; ++p) {
            const int c = p * 16 + cq;
            const float4 v = *reinterpret_cast<const float4*>(
                &X[((size_t)b * CH + c) * NT + n0 + nq]);
            T[nq + 0][c] = (f16)v.x;
            T[nq + 1][c] = (f16)v.y;
            T[nq + 2][c] = (f16)v.z;
            T[nq + 3][c] = (f16)v.w;
        }
    }
    __syncthreads();

    f32x4 acc[4][4] = {};   // [h][nt]

#pragma unroll 2
    for (int ks = 0; ks < 8; ++ks) {
        f16x8 bf[4];
#pragma unroll
        for (int nt = 0; nt < 4; ++nt)
            bf[nt] = *reinterpret_cast<const f16x8*>(
                &T[nt * 16 + lm][ks * 32 + lg * 8]);
#pragma unroll
        for (int h = 0; h < 4; ++h) {
            const f16x8 a = *reinterpret_cast<const f16x8*>(
                &W[(size_t)(h * 64 + w * 16 + lm) * CH + ks * 32 + lg * 8]);
#pragma unroll
            for (int nt = 0; nt < 4; ++nt)
                acc[h][nt] = MFMA16(a, bf[nt], acc[h][nt]);
        }
    }

    const int c_base = w * 16 + lg * 4;
    if (sel < 2) {
        f16* Out = sel == 0 ? Kt : Qt;
        const float sc = sel == 1 ? LOG2E : 1.0f;   // Q pre-scaled for exp2
#pragma unroll
        for (int h = 0; h < 4; ++h) {
            const float4 b4 = *reinterpret_cast<const float4*>(&Bi[h * 64 + c_base]);
            const float bb[4] = {b4.x, b4.y, b4.z, b4.w};
#pragma unroll
            for (int nt = 0; nt < 4; ++nt) {
                const int n = n0 + nt * 16 + lm;
                f16x4 o = {(f16)((acc[h][nt][0] + bb[0]) * sc),
                           (f16)((acc[h][nt][1] + bb[1]) * sc),
                           (f16)((acc[h][nt][2] + bb[2]) * sc),
                           (f16)((acc[h][nt][3] + bb[3]) * sc)};
                *reinterpret_cast<f16x4*>(
                    &Out[((size_t)((b * NHEADS + h) * NT + n)) * HC + c_base]) = o;
            }
        }
    } else {
        __syncthreads();   // x-tile dead; reuse SMEM as Vt[256][80]
#pragma unroll
        for (int h = 0; h < 4; ++h)
#pragma unroll
            for (int nt = 0; nt < 4; ++nt)
#pragma unroll
                for (int r = 0; r < 4; ++r)
                    Vt[h * 64 + c_base + r][nt * 16 + lm] = (f16)acc[h][nt][r];
        __syncthreads();
#pragma unroll
        for (int p = 0; p < 8; ++p) {
            const int c  = p * 32 + (t >> 3);
            const int nn = (t & 7) * 8;
            const float bb = Bi[c];
            const f16x8 vv = *reinterpret_cast<const f16x8*>(&Vt[c][nn]);
            f16x8 o;
#pragma unroll
            for (int j = 0; j < 8; ++j) o[j] = (f16)((float)vv[j] + bb);
            *reinterpret_cast<f16x8*>(
                &Vg[((size_t)((b * NHEADS + (c >> 6)) * HC + (c & 63))) * NT
                    + n0 + nn]) = o;
        }
    }
}

// ---------------------------------------------------------------------------
// Flash attention PASS 1 (R22 structure; exp via raw v_exp_f32).
// 128-query tiles, split-K x4, double-buffered one-barrier-per-chunk.
// grid 1152 = (18 qt x 4 seg x 16 bh, XCD-mapped), block 256 = 4 waves x 32q.
// ---------------------------------------------------------------------------
__global__ __launch_bounds__(256) void attn_p1(
    const f16* __restrict__ Kt, const f16* __restrict__ Qt,
    const f16* __restrict__ Vg,
    f16* __restrict__ Pa, float* __restrict__ Pm, float* __restrict__ Pl)
{
    __shared__ f16 SM[2][2][4096];   // [buf][K/V][64 rows x 64c], 32 KB

    const int t = threadIdx.x, l = t & 63, w = t >> 6;
    const int col = l & 31, hi = l >> 5;

    const int bid = blockIdx.x;
    const int xcd = bid & 7, idx = bid >> 3;          // 144 per XCD
    const int second = idx >= 72 ? 1 : 0;
    const int bh = 2 * xcd + second;                  // 2 (b,h) pairs per XCD
    const int idx2 = idx - 72 * second;               // 0..71
    const int qt = idx2 >> 2, seg = idx2 & 3;
    const int b = bh >> 2, h = bh & 3;
    const int m0 = qt * 128;

    const size_t bhs = (size_t)(b * NHEADS + h);
    const f16* Kb = Kt + bhs * NT * HC;   // [n][64c]
    const f16* Qb = Qt + bhs * NT * HC;
    const f16* Vb = Vg + bhs * HC * NT;   // [c][n]

    const int srow = l >> 3, su = l & 7, sx = su ^ srow;

    const int q = m0 + w * 32 + col;
    f16x8 qf[4];
#pragma unroll
    for (int cs = 0; cs < 4; ++cs)
        qf[cs] = *reinterpret_cast<const f16x8*>(
            &Qb[(size_t)q * HC + cs * 16 + hi * 8]);

    const f32x16 Z16 = {0,0,0,0,0,0,0,0,0,0,0,0,0,0,0,0};
    f32x16 acc0 = Z16, acc1 = Z16;
    float m_run = -3.0e38f, l_run = 0.0f;

    const int kbase = seg * KSEG;

    auto stage = [&](int kc, int buf) {
        const int half = (w & 1) * 32;
        if (w < 2) {
            const char* src = (const char*)(Kb + (size_t)kc * HC);
            char* dst = (char*)&SM[buf][0][0];
#pragma unroll
            for (int g = 0; g < 4; ++g) {
                const int rb = half + g * 8;
                gload_lds16(src + (size_t)(rb + srow) * 128 + (sx << 4),
                            dst + rb * 128);
            }
        } else {
            const char* src = (const char*)Vb + (size_t)kc * 2;
            char* dst = (char*)&SM[buf][1][0];
#pragma unroll
            for (int g = 0; g < 4; ++g) {
                const int rb = half + g * 8;
                gload_lds16(src + (size_t)(rb + srow) * (NT * 2) + (sx << 4),
                            dst + rb * 128);
            }
        }
    };

    auto rd = [&](const f16* base, int row, int u) -> f16x8 {
        return *reinterpret_cast<const f16x8*>(
            base + row * 64 + ((u ^ (row & 7)) << 3));
    };

    stage(kbase, 0);
    __syncthreads();

    for (int i = 0; i < NSEG; ++i) {
        const int cur = i & 1;
        if (i + 1 < NSEG) stage(kbase + (i + 1) * 64, cur ^ 1);

        const f16* Kc = &SM[cur][0][0];
        const f16* Vc = &SM[cur][1][0];

        f32x16 s0 = Z16, s1 = Z16;
#pragma unroll
        for (int cs = 0; cs < 4; ++cs) {
            const f16x8 k0 = rd(Kc, col,      cs * 2 + hi);
            const f16x8 k1 = rd(Kc, 32 + col, cs * 2 + hi);
            s0 = MFMA32(k0, qf[cs], s0);
            s1 = MFMA32(k1, qf[cs], s1);
        }

        float m8[8];
#pragma unroll
        for (int j = 0; j < 8; ++j)
            m8[j] = fmaxf(fmaxf(s0[2 * j], s0[2 * j + 1]),
                          fmaxf(s1[2 * j], s1[2 * j + 1]));
        float cm = fmaxf(fmaxf(fmaxf(m8[0], m8[1]), fmaxf(m8[2], m8[3])),
                         fmaxf(fmaxf(m8[4], m8[5]), fmaxf(m8[6], m8[7])));
        cm = fmaxf(cm, __shfl_xor(cm, 32));
        if (!__all(cm <= m_run + THR2)) {     // defer-max (log2 domain)
            const float mN = fmaxf(m_run, cm);
            const float fac = ex2(m_run - mN);
#pragma unroll
            for (int r = 0; r < 16; ++r) { acc0[r] *= fac; acc1[r] *= fac; }
            l_run *= fac;
            m_run = mN;
        }
        float p0[16], p1[16];
        float ps0 = 0.f, ps1 = 0.f, ps2 = 0.f, ps3 = 0.f;
#pragma unroll
        for (int r = 0; r < 4; ++r) {
            p0[r]      = ex2(s0[r]      - m_run); ps0 += p0[r];
            p0[r + 4]  = ex2(s0[r + 4]  - m_run); ps1 += p0[r + 4];
            p0[r + 8]  = ex2(s0[r + 8]  - m_run); ps2 += p0[r + 8];
            p0[r + 12] = ex2(s0[r + 12] - m_run); ps3 += p0[r + 12];
            p1[r]      = ex2(s1[r]      - m_run); ps0 += p1[r];
            p1[r + 4]  = ex2(s1[r + 4]  - m_run); ps1 += p1[r + 4];
            p1[r + 8]  = ex2(s1[r + 8]  - m_run); ps2 += p1[r + 8];
            p1[r + 12] = ex2(s1[r + 12] - m_run); ps3 += p1[r + 12];
        }
        l_run += (ps0 + ps1) + (ps2 + ps3);

        unsigned a0[8], a1[8];
#pragma unroll
        for (int j = 0; j < 8; ++j) {
            a0[j] = pkh(p0[2 * j], p0[2 * j + 1]);
            a1[j] = pkh(p1[2 * j], p1[2 * j + 1]);
        }
        swap32(a0[0], a0[2]); swap32(a0[1], a0[3]);
        swap32(a0[4], a0[6]); swap32(a0[5], a0[7]);
        swap32(a1[0], a1[2]); swap32(a1[1], a1[3]);
        swap32(a1[4], a1[6]); swap32(a1[5], a1[7]);
        union BU { unsigned u[4]; f16x8 v; };
        BU fr[4];
        fr[0].u[0] = a0[0]; fr[0].u[1] = a0[1]; fr[0].u[2] = a0[2]; fr[0].u[3] = a0[3];
        fr[1].u[0] = a0[4]; fr[1].u[1] = a0[5]; fr[1].u[2] = a0[6]; fr[1].u[3] = a0[7];
        fr[2].u[0] = a1[0]; fr[2].u[1] = a1[1]; fr[2].u[2] = a1[2]; fr[2].u[3] = a1[3];
        fr[3].u[0] = a1[4]; fr[3].u[1] = a1[5]; fr[3].u[2] = a1[6]; fr[3].u[3] = a1[7];

#pragma unroll
        for (int kk = 0; kk < 4; ++kk) {
            const f16x8 v0 = rd(Vc, col,      kk * 2 + hi);
            const f16x8 v1 = rd(Vc, 32 + col, kk * 2 + hi);
            acc0 = MFMA32(v0, fr[kk].v, acc0);
            acc1 = MFMA32(v1, fr[kk].v, acc1);
        }

        __syncthreads();   // publishes prefetch; frees buf for i+1's stage
    }

    // ---- publish normalized partials (m in log2 domain) -----------------
    const float l_full = l_run + __shfl_xor(l_run, 32);
    const float inv = 1.0f / l_full;
    const size_t pq = ((size_t)((seg * 16 + bh) * NQT + qt)) * 128 + w * 32 + col;
    if (hi == 0) { Pm[pq] = m_run; Pl[pq] = l_full; }
    f16* row = Pa + pq * 64;
#pragma unroll
    for (int rq = 0; rq < 4; ++rq) {
        const int c0 = rq * 8 + hi * 4;
        f16x4 o0 = {(f16)(acc0[rq * 4 + 0] * inv), (f16)(acc0[rq * 4 + 1] * inv),
                    (f16)(acc0[rq * 4 + 2] * inv), (f16)(acc0[rq * 4 + 3] * inv)};
        f16x4 o1 = {(f16)(acc1[rq * 4 + 0] * inv), (f16)(acc1[rq * 4 + 1] * inv),
                    (f16)(acc1[rq * 4 + 2] * inv), (f16)(acc1[rq * 4 + 3] * inv)};
        *reinterpret_cast<f16x4*>(row + c0) = o0;
        *reinterpret_cast<f16x4*>(row + 32 + c0) = o1;
    }
}

// ---------------------------------------------------------------------------
// FUSED merge + final conv1x1 (R22's 64-row version; exp2 weights).
// grid (36, 4) = (ntile64, b), block 256.
// ---------------------------------------------------------------------------
__global__ __launch_bounds__(256) void out_fused(
    const f16* __restrict__ wo16, const float* __restrict__ bo,
    const f16* __restrict__ Pa, const float* __restrict__ Pm,
    const float* __restrict__ Pl, float* __restrict__ Y)
{
    __shared__ f16 T[64][264];   // merged attention output tile [n][c]

    const int t = threadIdx.x, l = t & 63, w = t >> 6;
    const int lm = l & 15, lg = l >> 4;
    const int n0 = blockIdx.x * 64;
    const int b = blockIdx.y;
    const int qt = n0 >> 7, ql0 = n0 & 127;

    // ---- phase 1: merge. thread t: query row n = t>>2, 16 ch c16 = (t&3)*16
    {
        const int n = t >> 2, c16 = (t & 3) * 16;
#pragma unroll
        for (int h = 0; h < 4; ++h) {
            const int bh = b * NHEADS + h;
            size_t ix[NSEGS];
            float m[NSEGS], c[NSEGS];
            float M = -3.0e38f;
#pragma unroll
            for (int s = 0; s < NSEGS; ++s) {
                ix[s] = ((size_t)((s * 16 + bh) * NQT + qt)) * 128 + ql0 + n;
                m[s] = Pm[ix[s]];
                M = fmaxf(M, m[s]);
            }
            float csum = 0.f;
#pragma unroll
            for (int s = 0; s < NSEGS; ++s) {
                c[s] = ex2(m[s] - M) * Pl[ix[s]];
                csum += c[s];
            }
            const float inv = 1.0f / csum;
            float v[16] = {};
#pragma unroll
            for (int s = 0; s < NSEGS; ++s) {
                const f16* r = Pa + ix[s] * 64 + c16;
                const f16x8 a0 = *reinterpret_cast<const f16x8*>(r);
                const f16x8 a1 = *reinterpret_cast<const f16x8*>(r + 8);
#pragma unroll
                for (int j = 0; j < 8; ++j) {
                    v[j]     += c[s] * (float)a0[j];
                    v[8 + j] += c[s] * (float)a1[j];
                }
            }
            f16x8 o0, o1;
#pragma unroll
            for (int j = 0; j < 8; ++j) {
                o0[j] = (f16)(v[j] * inv);
                o1[j] = (f16)(v[8 + j] * inv);
            }
            *reinterpret_cast<f16x8*>(&T[n][h * 64 + c16]) = o0;
            *reinterpret_cast<f16x8*>(&T[n][h * 64 + c16 + 8]) = o1;
        }
    }
    __syncthreads();

    // ---- phase 2: GEMM (proj_v3 structure), all 4 o-tiles ----------------
    f32x4 acc[4][4] = {};   // [h'][nt]
#pragma unroll 2
    for (int ks = 0; ks < 8; ++ks) {
        f16x8 bf[4];
#pragma unroll
        for (int nt = 0; nt < 4; ++nt)
            bf[nt] = *reinterpret_cast<const f16x8*>(
                &T[nt * 16 + lm][ks * 32 + lg * 8]);
#pragma unroll
        for (int hp = 0; hp < 4; ++hp) {
            const f16x8 a = *reinterpret_cast<const f16x8*>(
                &wo16[(size_t)(hp * 64 + w * 16 + lm) * CH + ks * 32 + lg * 8]);
#pragma unroll
            for (int nt = 0; nt < 4; ++nt)
                acc[hp][nt] = MFMA16(a, bf[nt], acc[hp][nt]);
        }
    }

    const int c_base = w * 16 + lg * 4;
#pragma unroll
    for (int hp = 0; hp < 4; ++hp) {
        const float4 b4 = *reinterpret_cast<const float4*>(&bo[hp * 64 + c_base]);
        const float bb[4] = {b4.x, b4.y, b4.z, b4.w};
#pragma unroll
        for (int nt = 0; nt < 4; ++nt) {
            const int n = n0 + nt * 16 + lm;
#pragma unroll
            for (int r = 0; r < 4; ++r)
                Y[((size_t)(b * CH + hp * 64 + c_base + r)) * NT + n] =
                    acc[hp][nt][r] + bb[r];
        }
    }
}

// ---------------------------------------------------------------------------
extern "C" void kernel_launch(void* const* d_in, const int* in_sizes, int n_in,
                              void* d_out, int out_size, void* d_ws, size_t ws_size,
                              hipStream_t stream) {
    (void)in_sizes; (void)n_in; (void)out_size; (void)ws_size;
    const float* x  = (const float*)d_in[0];
    const float* wk = (const float*)d_in[1];
    const float* bk = (const float*)d_in[2];
    const float* wq = (const float*)d_in[3];
    const float* bq = (const float*)d_in[4];
    const float* wv = (const float*)d_in[5];
    const float* bv = (const float*)d_in[6];
    const float* wo = (const float*)d_in[7];
    const float* bo = (const float*)d_in[8];
    float* out = (float*)d_out;

    const size_t SZ = (size_t)NB * NT * CH;           // 2,359,296 f16 per tensor
    f16* Kt  = (f16*)d_ws;                            // [b][h][n][c]
    f16* Qt  = Kt + SZ;                               // [b][h][n][c] (pre-scaled)
    f16* Vg  = Qt + SZ;                               // [b][h][c][n]
    f16* W16 = Vg + SZ;                               // [4][65536] f16
    f16* Pa  = W16 + 4 * 65536;                       // [4][16][18][128][64] f16
    float* Pm = (float*)(Pa + (size_t)NSEGS * 16 * NQT * 128 * 64);
    float* Pl = Pm + (size_t)NSEGS * 16 * NQT * 128;  // total ws ~34 MB

    wcvt<<<dim3(128), 256, 0, stream>>>(wk, wq, wv, wo, W16);
    proj_qkv_v3<<<dim3(36, 3, 4), 256, 0, stream>>>(
        W16, bk, bq, bv, x, Kt, Qt, Vg);
    attn_p1<<<dim3(1152), 256, 0, stream>>>(Kt, Qt, Vg, Pa, Pm, Pl);
    out_fused<<<dim3(36, 4), 256, 0, stream>>>(
        W16 + 3 * 65536, bo, Pa, Pm, Pl, out);
}

// Round 25
// 82.888 us; speedup vs baseline: 1.2176x; 1.0204x over previous
//
#include <hip/hip_runtime.h>
#include <math.h>

#define NB 4
#define CH 256
#define NHEADS 4
#define HC 64
#define NT 2304    // 48*48
#define NSEGS 4    // split-K segments (cross-block)
#define KSEG 576   // keys per segment
#define NSEG 9     // 64-key chunks per segment
#define NQT 18     // 128-query tiles
#define LOG2E 1.44269504f
#define THR2 11.541561f   // 8 * log2(e): defer-max threshold, log2 domain

typedef _Float16 f16;
typedef _Float16 f16x4 __attribute__((ext_vector_type(4)));
typedef _Float16 f16x8 __attribute__((ext_vector_type(8)));
typedef float f32x4 __attribute__((ext_vector_type(4)));
typedef float f32x16 __attribute__((ext_vector_type(16)));

#define MFMA16(a, b, c) __builtin_amdgcn_mfma_f32_16x16x32_f16(a, b, c, 0, 0, 0)
#define MFMA32(a, b, c) __builtin_amdgcn_mfma_f32_32x32x16_f16(a, b, c, 0, 0, 0)

__device__ __forceinline__ void gload_lds16(const void* g, void* l) {
    __builtin_amdgcn_global_load_lds(
        (const __attribute__((address_space(1))) unsigned int*)g,
        (__attribute__((address_space(3))) unsigned int*)l, 16, 0, 0);
}

__device__ __forceinline__ unsigned pkh(float a, float b) {
    auto r = __builtin_amdgcn_cvt_pkrtz(a, b);   // __fp16 ext_vector(2)
    return __builtin_bit_cast(unsigned, r);
}
__device__ __forceinline__ void swap32(unsigned& a, unsigned& b) {
    asm volatile("v_permlane32_swap_b32 %0, %1" : "+v"(a), "+v"(b));
}
// raw v_exp_f32: D = 2^S0 (single VOP1; Q is pre-scaled by log2e upstream)
__device__ __forceinline__ float ex2(float x) {
    float r;
    asm("v_exp_f32 %0, %1" : "=v"(r) : "v"(x));
    return r;
}

// ---------------------------------------------------------------------------
// Weight f32 -> f16 pre-conversion (wk, wq, wv, wo -> W16[4][65536]).
// ---------------------------------------------------------------------------
__global__ __launch_bounds__(256) void wcvt(
    const float* __restrict__ w0, const float* __restrict__ w1,
    const float* __restrict__ w2, const float* __restrict__ w3,
    f16* __restrict__ O)
{
    const int id = blockIdx.x * 256 + threadIdx.x;   // 0..32767
    const int tsel = id >> 13;                        // 0..3
    const int off = (id & 8191) * 8;
    const float* src = tsel == 0 ? w0 : (tsel == 1 ? w1 : (tsel == 2 ? w2 : w3));
    const float4 a = *reinterpret_cast<const float4*>(src + off);
    const float4 b = *reinterpret_cast<const float4*>(src + off + 4);
    f16x8 o = {(f16)a.x, (f16)a.y, (f16)a.z, (f16)a.w,
               (f16)b.x, (f16)b.y, (f16)b.z, (f16)b.w};
    *reinterpret_cast<f16x8*>(&O[(size_t)tsel * 65536 + off]) = o;
}

// ---------------------------------------------------------------------------
// Fused K/Q/V projection (R24, unchanged). grid (36, 3, 4), block 256.
// Q pre-scaled by log2e for the exp2-domain softmax.
// ---------------------------------------------------------------------------
__global__ __launch_bounds__(256) void proj_qkv_v3(
    const f16* __restrict__ W16,
    const float* __restrict__ bk, const float* __restrict__ bq,
    const float* __restrict__ bv,
    const float* __restrict__ X,
    f16* __restrict__ Kt, f16* __restrict__ Qt, f16* __restrict__ Vg)
{
    __shared__ __align__(16) char SMEM[40960];
    f16 (*T)[264]  = reinterpret_cast<f16(*)[264]>(SMEM);   // x-tile [64n][256c+pad]
    f16 (*Vt)[80]  = reinterpret_cast<f16(*)[80]>(SMEM);    // V out  [256c][64n+pad]

    const int t = threadIdx.x, l = t & 63, w = t >> 6;
    const int lm = l & 15, lg = l >> 4;
    const int n0 = blockIdx.x * 64;
    const int sel = blockIdx.y;
    const int b = blockIdx.z;

    const f16* W = W16 + (size_t)sel * 65536;
    const float* Bi = sel == 0 ? bk : (sel == 1 ? bq : bv);

    {
        const int cq = t >> 4;
        const int nq = (t & 15) * 4;
#pragma unroll
        for (int p = 0; p < 16; ++p) {
            const int c = p * 16 + cq;
            const float4 v = *reinterpret_cast<const float4*>(
                &X[((size_t)b * CH + c) * NT + n0 + nq]);
            T[nq + 0][c] = (f16)v.x;
            T[nq + 1][c] = (f16)v.y;
            T[nq + 2][c] = (f16)v.z;
            T[nq + 3][c] = (f16)v.w;
        }
    }
    __syncthreads();

    f32x4 acc[4][4] = {};   // [h][nt]

#pragma unroll 2
    for (int ks = 0; ks < 8; ++ks) {
        f16x8 bf[4];
#pragma unroll
        for (int nt = 0; nt < 4; ++nt)
            bf[nt] = *reinterpret_cast<const f16x8*>(
                &T[nt * 16 + lm][ks * 32 + lg * 8]);
#pragma unroll
        for (int h = 0; h < 4; ++h) {
            const f16x8 a = *reinterpret_cast<const f16x8*>(
                &W[(size_t)(h * 64 + w * 16 + lm) * CH + ks * 32 + lg * 8]);
#pragma unroll
            for (int nt = 0; nt < 4; ++nt)
                acc[h][nt] = MFMA16(a, bf[nt], acc[h][nt]);
        }
    }

    const int c_base = w * 16 + lg * 4;
    if (sel < 2) {
        f16* Out = sel == 0 ? Kt : Qt;
        const float sc = sel == 1 ? LOG2E : 1.0f;   // Q pre-scaled for exp2
#pragma unroll
        for (int h = 0; h < 4; ++h) {
            const float4 b4 = *reinterpret_cast<const float4*>(&Bi[h * 64 + c_base]);
            const float bb[4] = {b4.x, b4.y, b4.z, b4.w};
#pragma unroll
            for (int nt = 0; nt < 4; ++nt) {
                const int n = n0 + nt * 16 + lm;
                f16x4 o = {(f16)((acc[h][nt][0] + bb[0]) * sc),
                           (f16)((acc[h][nt][1] + bb[1]) * sc),
                           (f16)((acc[h][nt][2] + bb[2]) * sc),
                           (f16)((acc[h][nt][3] + bb[3]) * sc)};
                *reinterpret_cast<f16x4*>(
                    &Out[((size_t)((b * NHEADS + h) * NT + n)) * HC + c_base]) = o;
            }
        }
    } else {
        __syncthreads();   // x-tile dead; reuse SMEM as Vt[256][80]
#pragma unroll
        for (int h = 0; h < 4; ++h)
#pragma unroll
            for (int nt = 0; nt < 4; ++nt)
#pragma unroll
                for (int r = 0; r < 4; ++r)
                    Vt[h * 64 + c_base + r][nt * 16 + lm] = (f16)acc[h][nt][r];
        __syncthreads();
#pragma unroll
        for (int p = 0; p < 8; ++p) {
            const int c  = p * 32 + (t >> 3);
            const int nn = (t & 7) * 8;
            const float bb = Bi[c];
            const f16x8 vv = *reinterpret_cast<const f16x8*>(&Vt[c][nn]);
            f16x8 o;
#pragma unroll
            for (int j = 0; j < 8; ++j) o[j] = (f16)((float)vv[j] + bb);
            *reinterpret_cast<f16x8*>(
                &Vg[((size_t)((b * NHEADS + (c >> 6)) * HC + (c & 63))) * NT
                    + n0 + nn]) = o;
        }
    }
}

// ---------------------------------------------------------------------------
// Flash attention PASS 1 (R24, unchanged): 128-query tiles, split-K x4,
// double-buffered one-barrier-per-chunk, exp2-domain softmax via v_exp_f32.
// grid 1152 = (18 qt x 4 seg x 16 bh, XCD-mapped), block 256 = 4 waves x 32q.
// ---------------------------------------------------------------------------
__global__ __launch_bounds__(256) void attn_p1(
    const f16* __restrict__ Kt, const f16* __restrict__ Qt,
    const f16* __restrict__ Vg,
    f16* __restrict__ Pa, float* __restrict__ Pm, float* __restrict__ Pl)
{
    __shared__ f16 SM[2][2][4096];   // [buf][K/V][64 rows x 64c], 32 KB

    const int t = threadIdx.x, l = t & 63, w = t >> 6;
    const int col = l & 31, hi = l >> 5;

    const int bid = blockIdx.x;
    const int xcd = bid & 7, idx = bid >> 3;          // 144 per XCD
    const int second = idx >= 72 ? 1 : 0;
    const int bh = 2 * xcd + second;                  // 2 (b,h) pairs per XCD
    const int idx2 = idx - 72 * second;               // 0..71
    const int qt = idx2 >> 2, seg = idx2 & 3;
    const int b = bh >> 2, h = bh & 3;
    const int m0 = qt * 128;

    const size_t bhs = (size_t)(b * NHEADS + h);
    const f16* Kb = Kt + bhs * NT * HC;   // [n][64c]
    const f16* Qb = Qt + bhs * NT * HC;
    const f16* Vb = Vg + bhs * HC * NT;   // [c][n]

    const int srow = l >> 3, su = l & 7, sx = su ^ srow;

    const int q = m0 + w * 32 + col;
    f16x8 qf[4];
#pragma unroll
    for (int cs = 0; cs < 4; ++cs)
        qf[cs] = *reinterpret_cast<const f16x8*>(
            &Qb[(size_t)q * HC + cs * 16 + hi * 8]);

    const f32x16 Z16 = {0,0,0,0,0,0,0,0,0,0,0,0,0,0,0,0};
    f32x16 acc0 = Z16, acc1 = Z16;
    float m_run = -3.0e38f, l_run = 0.0f;

    const int kbase = seg * KSEG;

    auto stage = [&](int kc, int buf) {
        const int half = (w & 1) * 32;
        if (w < 2) {
            const char* src = (const char*)(Kb + (size_t)kc * HC);
            char* dst = (char*)&SM[buf][0][0];
#pragma unroll
            for (int g = 0; g < 4; ++g) {
                const int rb = half + g * 8;
                gload_lds16(src + (size_t)(rb + srow) * 128 + (sx << 4),
                            dst + rb * 128);
            }
        } else {
            const char* src = (const char*)Vb + (size_t)kc * 2;
            char* dst = (char*)&SM[buf][1][0];
#pragma unroll
            for (int g = 0; g < 4; ++g) {
                const int rb = half + g * 8;
                gload_lds16(src + (size_t)(rb + srow) * (NT * 2) + (sx << 4),
                            dst + rb * 128);
            }
        }
    };

    auto rd = [&](const f16* base, int row, int u) -> f16x8 {
        return *reinterpret_cast<const f16x8*>(
            base + row * 64 + ((u ^ (row & 7)) << 3));
    };

    stage(kbase, 0);
    __syncthreads();

    for (int i = 0; i < NSEG; ++i) {
        const int cur = i & 1;
        if (i + 1 < NSEG) stage(kbase + (i + 1) * 64, cur ^ 1);

        const f16* Kc = &SM[cur][0][0];
        const f16* Vc = &SM[cur][1][0];

        f32x16 s0 = Z16, s1 = Z16;
#pragma unroll
        for (int cs = 0; cs < 4; ++cs) {
            const f16x8 k0 = rd(Kc, col,      cs * 2 + hi);
            const f16x8 k1 = rd(Kc, 32 + col, cs * 2 + hi);
            s0 = MFMA32(k0, qf[cs], s0);
            s1 = MFMA32(k1, qf[cs], s1);
        }

        float m8[8];
#pragma unroll
        for (int j = 0; j < 8; ++j)
            m8[j] = fmaxf(fmaxf(s0[2 * j], s0[2 * j + 1]),
                          fmaxf(s1[2 * j], s1[2 * j + 1]));
        float cm = fmaxf(fmaxf(fmaxf(m8[0], m8[1]), fmaxf(m8[2], m8[3])),
                         fmaxf(fmaxf(m8[4], m8[5]), fmaxf(m8[6], m8[7])));
        cm = fmaxf(cm, __shfl_xor(cm, 32));
        if (!__all(cm <= m_run + THR2)) {     // defer-max (log2 domain)
            const float mN = fmaxf(m_run, cm);
            const float fac = ex2(m_run - mN);
#pragma unroll
            for (int r = 0; r < 16; ++r) { acc0[r] *= fac; acc1[r] *= fac; }
            l_run *= fac;
            m_run = mN;
        }
        float p0[16], p1[16];
        float ps0 = 0.f, ps1 = 0.f, ps2 = 0.f, ps3 = 0.f;
#pragma unroll
        for (int r = 0; r < 4; ++r) {
            p0[r]      = ex2(s0[r]      - m_run); ps0 += p0[r];
            p0[r + 4]  = ex2(s0[r + 4]  - m_run); ps1 += p0[r + 4];
            p0[r + 8]  = ex2(s0[r + 8]  - m_run); ps2 += p0[r + 8];
            p0[r + 12] = ex2(s0[r + 12] - m_run); ps3 += p0[r + 12];
            p1[r]      = ex2(s1[r]      - m_run); ps0 += p1[r];
            p1[r + 4]  = ex2(s1[r + 4]  - m_run); ps1 += p1[r + 4];
            p1[r + 8]  = ex2(s1[r + 8]  - m_run); ps2 += p1[r + 8];
            p1[r + 12] = ex2(s1[r + 12] - m_run); ps3 += p1[r + 12];
        }
        l_run += (ps0 + ps1) + (ps2 + ps3);

        unsigned a0[8], a1[8];
#pragma unroll
        for (int j = 0; j < 8; ++j) {
            a0[j] = pkh(p0[2 * j], p0[2 * j + 1]);
            a1[j] = pkh(p1[2 * j], p1[2 * j + 1]);
        }
        swap32(a0[0], a0[2]); swap32(a0[1], a0[3]);
        swap32(a0[4], a0[6]); swap32(a0[5], a0[7]);
        swap32(a1[0], a1[2]); swap32(a1[1], a1[3]);
        swap32(a1[4], a1[6]); swap32(a1[5], a1[7]);
        union BU { unsigned u[4]; f16x8 v; };
        BU fr[4];
        fr[0].u[0] = a0[0]; fr[0].u[1] = a0[1]; fr[0].u[2] = a0[2]; fr[0].u[3] = a0[3];
        fr[1].u[0] = a0[4]; fr[1].u[1] = a0[5]; fr[1].u[2] = a0[6]; fr[1].u[3] = a0[7];
        fr[2].u[0] = a1[0]; fr[2].u[1] = a1[1]; fr[2].u[2] = a1[2]; fr[2].u[3] = a1[3];
        fr[3].u[0] = a1[4]; fr[3].u[1] = a1[5]; fr[3].u[2] = a1[6]; fr[3].u[3] = a1[7];

#pragma unroll
        for (int kk = 0; kk < 4; ++kk) {
            const f16x8 v0 = rd(Vc, col,      kk * 2 + hi);
            const f16x8 v1 = rd(Vc, 32 + col, kk * 2 + hi);
            acc0 = MFMA32(v0, fr[kk].v, acc0);
            acc1 = MFMA32(v1, fr[kk].v, acc1);
        }

        __syncthreads();   // publishes prefetch; frees buf for i+1's stage
    }

    // ---- publish normalized partials (m in log2 domain) -----------------
    const float l_full = l_run + __shfl_xor(l_run, 32);
    const float inv = 1.0f / l_full;
    const size_t pq = ((size_t)((seg * 16 + bh) * NQT + qt)) * 128 + w * 32 + col;
    if (hi == 0) { Pm[pq] = m_run; Pl[pq] = l_full; }
    f16* row = Pa + pq * 64;
#pragma unroll
    for (int rq = 0; rq < 4; ++rq) {
        const int c0 = rq * 8 + hi * 4;
        f16x4 o0 = {(f16)(acc0[rq * 4 + 0] * inv), (f16)(acc0[rq * 4 + 1] * inv),
                    (f16)(acc0[rq * 4 + 2] * inv), (f16)(acc0[rq * 4 + 3] * inv)};
        f16x4 o1 = {(f16)(acc1[rq * 4 + 0] * inv), (f16)(acc1[rq * 4 + 1] * inv),
                    (f16)(acc1[rq * 4 + 2] * inv), (f16)(acc1[rq * 4 + 3] * inv)};
        *reinterpret_cast<f16x4*>(row + c0) = o0;
        *reinterpret_cast<f16x4*>(row + 32 + c0) = o1;
    }
}

// ---------------------------------------------------------------------------
// FUSED merge + final conv1x1, HEAD-SPLIT for occupancy.
// grid (36, 4, 2) = (ntile64, b, head-pair) -> 288 blocks (1.125/CU, 2x R24).
// Per-block W reads halve (2 o-tiles) so TOTAL W traffic is unchanged;
// only the Pa merge-read duplicates (+9.4 MB, L2-cheap).
// Phase 1: 4-way exact merge (exp2 weights) -> LDS T[64][264] (all 4 h).
// Phase 2: GEMM over THIS BLOCK'S 2 o-tiles; write Y f32 + bias.
// ---------------------------------------------------------------------------
__global__ __launch_bounds__(256) void out_fused(
    const f16* __restrict__ wo16, const float* __restrict__ bo,
    const f16* __restrict__ Pa, const float* __restrict__ Pm,
    const float* __restrict__ Pl, float* __restrict__ Y)
{
    __shared__ f16 T[64][264];   // merged attention output tile [n][c]

    const int t = threadIdx.x, l = t & 63, w = t >> 6;
    const int lm = l & 15, lg = l >> 4;
    const int n0 = blockIdx.x * 64;
    const int b = blockIdx.y;
    const int hz = blockIdx.z;            // head-pair: o-tiles {2hz, 2hz+1}
    const int qt = n0 >> 7, ql0 = n0 & 127;

    // ---- phase 1: merge (all 4 heads; K-dim of the GEMM needs full 256c)
    {
        const int n = t >> 2, c16 = (t & 3) * 16;
#pragma unroll
        for (int h = 0; h < 4; ++h) {
            const int bh = b * NHEADS + h;
            size_t ix[NSEGS];
            float m[NSEGS], c[NSEGS];
            float M = -3.0e38f;
#pragma unroll
            for (int s = 0; s < NSEGS; ++s) {
                ix[s] = ((size_t)((s * 16 + bh) * NQT + qt)) * 128 + ql0 + n;
                m[s] = Pm[ix[s]];
                M = fmaxf(M, m[s]);
            }
            float csum = 0.f;
#pragma unroll
            for (int s = 0; s < NSEGS; ++s) {
                c[s] = ex2(m[s] - M) * Pl[ix[s]];
                csum += c[s];
            }
            const float inv = 1.0f / csum;
            float v[16] = {};
#pragma unroll
            for (int s = 0; s < NSEGS; ++s) {
                const f16* r = Pa + ix[s] * 64 + c16;
                const f16x8 a0 = *reinterpret_cast<const f16x8*>(r);
                const f16x8 a1 = *reinterpret_cast<const f16x8*>(r + 8);
#pragma unroll
                for (int j = 0; j < 8; ++j) {
                    v[j]     += c[s] * (float)a0[j];
                    v[8 + j] += c[s] * (float)a1[j];
                }
            }
            f16x8 o0, o1;
#pragma unroll
            for (int j = 0; j < 8; ++j) {
                o0[j] = (f16)(v[j] * inv);
                o1[j] = (f16)(v[8 + j] * inv);
            }
            *reinterpret_cast<f16x8*>(&T[n][h * 64 + c16]) = o0;
            *reinterpret_cast<f16x8*>(&T[n][h * 64 + c16 + 8]) = o1;
        }
    }
    __syncthreads();

    // ---- phase 2: GEMM over this block's 2 o-tiles -----------------------
    f32x4 acc[2][4] = {};   // [hp][nt]
#pragma unroll 2
    for (int ks = 0; ks < 8; ++ks) {
        f16x8 bf[4];
#pragma unroll
        for (int nt = 0; nt < 4; ++nt)
            bf[nt] = *reinterpret_cast<const f16x8*>(
                &T[nt * 16 + lm][ks * 32 + lg * 8]);
#pragma unroll
        for (int hp = 0; hp < 2; ++hp) {
            const int oo = (hz * 2 + hp) * 64;
            const f16x8 a = *reinterpret_cast<const f16x8*>(
                &wo16[(size_t)(oo + w * 16 + lm) * CH + ks * 32 + lg * 8]);
#pragma unroll
            for (int nt = 0; nt < 4; ++nt)
                acc[hp][nt] = MFMA16(a, bf[nt], acc[hp][nt]);
        }
    }

    const int c_base = w * 16 + lg * 4;
#pragma unroll
    for (int hp = 0; hp < 2; ++hp) {
        const int oo = (hz * 2 + hp) * 64;
        const float4 b4 = *reinterpret_cast<const float4*>(&bo[oo + c_base]);
        const float bb[4] = {b4.x, b4.y, b4.z, b4.w};
#pragma unroll
        for (int nt = 0; nt < 4; ++nt) {
            const int n = n0 + nt * 16 + lm;
#pragma unroll
            for (int r = 0; r < 4; ++r)
                Y[((size_t)(b * CH + oo + c_base + r)) * NT + n] =
                    acc[hp][nt][r] + bb[r];
        }
    }
}

// ---------------------------------------------------------------------------
extern "C" void kernel_launch(void* const* d_in, const int* in_sizes, int n_in,
                              void* d_out, int out_size, void* d_ws, size_t ws_size,
                              hipStream_t stream) {
    (void)in_sizes; (void)n_in; (void)out_size; (void)ws_size;
    const float* x  = (const float*)d_in[0];
    const float* wk = (const float*)d_in[1];
    const float* bk = (const float*)d_in[2];
    const float* wq = (const float*)d_in[3];
    const float* bq = (const float*)d_in[4];
    const float* wv = (const float*)d_in[5];
    const float* bv = (const float*)d_in[6];
    const float* wo = (const float*)d_in[7];
    const float* bo = (const float*)d_in[8];
    float* out = (float*)d_out;

    const size_t SZ = (size_t)NB * NT * CH;           // 2,359,296 f16 per tensor
    f16* Kt  = (f16*)d_ws;                            // [b][h][n][c]
    f16* Qt  = Kt + SZ;                               // [b][h][n][c] (pre-scaled)
    f16* Vg  = Qt + SZ;                               // [b][h][c][n]
    f16* W16 = Vg + SZ;                               // [4][65536] f16
    f16* Pa  = W16 + 4 * 65536;                       // [4][16][18][128][64] f16
    float* Pm = (float*)(Pa + (size_t)NSEGS * 16 * NQT * 128 * 64);
    float* Pl = Pm + (size_t)NSEGS * 16 * NQT * 128;  // total ws ~34 MB

    wcvt<<<dim3(128), 256, 0, stream>>>(wk, wq, wv, wo, W16);
    proj_qkv_v3<<<dim3(36, 3, 4), 256, 0, stream>>>(
        W16, bk, bq, bv, x, Kt, Qt, Vg);
    attn_p1<<<dim3(1152), 256, 0, stream>>>(Kt, Qt, Vg, Pa, Pm, Pl);
    out_fused<<<dim3(36, 4, 2), 256, 0, stream>>>(
        W16 + 3 * 65536, bo, Pa, Pm, Pl, out);
}

// Round 26
// 81.478 us; speedup vs baseline: 1.2387x; 1.0173x over previous
//
#include <hip/hip_runtime.h>
#include <math.h>

#define NB 4
#define CH 256
#define NHEADS 4
#define HC 64
#define NT 2304    // 48*48
#define NSEGS 4    // split-K segments (cross-block)
#define KSEG 576   // keys per segment
#define NSEG 9     // 64-key chunks per segment
#define NQT 9      // 256-query tiles
#define QTILE 256
#define LOG2E 1.44269504f
#define THR2 11.541561f   // 8 * log2(e): defer-max threshold, log2 domain

typedef _Float16 f16;
typedef _Float16 f16x4 __attribute__((ext_vector_type(4)));
typedef _Float16 f16x8 __attribute__((ext_vector_type(8)));
typedef float f32x4 __attribute__((ext_vector_type(4)));
typedef float f32x16 __attribute__((ext_vector_type(16)));

#define MFMA16(a, b, c) __builtin_amdgcn_mfma_f32_16x16x32_f16(a, b, c, 0, 0, 0)
#define MFMA32(a, b, c) __builtin_amdgcn_mfma_f32_32x32x16_f16(a, b, c, 0, 0, 0)

__device__ __forceinline__ void gload_lds16(const void* g, void* l) {
    __builtin_amdgcn_global_load_lds(
        (const __attribute__((address_space(1))) unsigned int*)g,
        (__attribute__((address_space(3))) unsigned int*)l, 16, 0, 0);
}

__device__ __forceinline__ unsigned pkh(float a, float b) {
    auto r = __builtin_amdgcn_cvt_pkrtz(a, b);   // __fp16 ext_vector(2)
    return __builtin_bit_cast(unsigned, r);
}
__device__ __forceinline__ void swap32(unsigned& a, unsigned& b) {
    asm volatile("v_permlane32_swap_b32 %0, %1" : "+v"(a), "+v"(b));
}
// raw v_exp_f32: D = 2^S0 (single VOP1; Q is pre-scaled by log2e upstream)
__device__ __forceinline__ float ex2(float x) {
    float r;
    asm("v_exp_f32 %0, %1" : "=v"(r) : "v"(x));
    return r;
}

// ---------------------------------------------------------------------------
// Weight f32 -> f16 pre-conversion (wk, wq, wv, wo -> W16[4][65536]).
// ---------------------------------------------------------------------------
__global__ __launch_bounds__(256) void wcvt(
    const float* __restrict__ w0, const float* __restrict__ w1,
    const float* __restrict__ w2, const float* __restrict__ w3,
    f16* __restrict__ O)
{
    const int id = blockIdx.x * 256 + threadIdx.x;   // 0..32767
    const int tsel = id >> 13;                        // 0..3
    const int off = (id & 8191) * 8;
    const float* src = tsel == 0 ? w0 : (tsel == 1 ? w1 : (tsel == 2 ? w2 : w3));
    const float4 a = *reinterpret_cast<const float4*>(src + off);
    const float4 b = *reinterpret_cast<const float4*>(src + off + 4);
    f16x8 o = {(f16)a.x, (f16)a.y, (f16)a.z, (f16)a.w,
               (f16)b.x, (f16)b.y, (f16)b.z, (f16)b.w};
    *reinterpret_cast<f16x8*>(&O[(size_t)tsel * 65536 + off]) = o;
}

// ---------------------------------------------------------------------------
// Fused K/Q/V projection (R24/R25, unchanged). grid (36, 3, 4), block 256.
// Q pre-scaled by log2e for the exp2-domain softmax.
// ---------------------------------------------------------------------------
__global__ __launch_bounds__(256) void proj_qkv_v3(
    const f16* __restrict__ W16,
    const float* __restrict__ bk, const float* __restrict__ bq,
    const float* __restrict__ bv,
    const float* __restrict__ X,
    f16* __restrict__ Kt, f16* __restrict__ Qt, f16* __restrict__ Vg)
{
    __shared__ __align__(16) char SMEM[40960];
    f16 (*T)[264]  = reinterpret_cast<f16(*)[264]>(SMEM);   // x-tile [64n][256c+pad]
    f16 (*Vt)[80]  = reinterpret_cast<f16(*)[80]>(SMEM);    // V out  [256c][64n+pad]

    const int t = threadIdx.x, l = t & 63, w = t >> 6;
    const int lm = l & 15, lg = l >> 4;
    const int n0 = blockIdx.x * 64;
    const int sel = blockIdx.y;
    const int b = blockIdx.z;

    const f16* W = W16 + (size_t)sel * 65536;
    const float* Bi = sel == 0 ? bk : (sel == 1 ? bq : bv);

    {
        const int cq = t >> 4;
        const int nq = (t & 15) * 4;
#pragma unroll
        for (int p = 0; p < 16; ++p) {
            const int c = p * 16 + cq;
            const float4 v = *reinterpret_cast<const float4*>(
                &X[((size_t)b * CH + c) * NT + n0 + nq]);
            T[nq + 0][c] = (f16)v.x;
            T[nq + 1][c] = (f16)v.y;
            T[nq + 2][c] = (f16)v.z;
            T[nq + 3][c] = (f16)v.w;
        }
    }
    __syncthreads();

    f32x4 acc[4][4] = {};   // [h][nt]

#pragma unroll 2
    for (int ks = 0; ks < 8; ++ks) {
        f16x8 bf[4];
#pragma unroll
        for (int nt = 0; nt < 4; ++nt)
            bf[nt] = *reinterpret_cast<const f16x8*>(
                &T[nt * 16 + lm][ks * 32 + lg * 8]);
#pragma unroll
        for (int h = 0; h < 4; ++h) {
            const f16x8 a = *reinterpret_cast<const f16x8*>(
                &W[(size_t)(h * 64 + w * 16 + lm) * CH + ks * 32 + lg * 8]);
#pragma unroll
            for (int nt = 0; nt < 4; ++nt)
                acc[h][nt] = MFMA16(a, bf[nt], acc[h][nt]);
        }
    }

    const int c_base = w * 16 + lg * 4;
    if (sel < 2) {
        f16* Out = sel == 0 ? Kt : Qt;
        const float sc = sel == 1 ? LOG2E : 1.0f;   // Q pre-scaled for exp2
#pragma unroll
        for (int h = 0; h < 4; ++h) {
            const float4 b4 = *reinterpret_cast<const float4*>(&Bi[h * 64 + c_base]);
            const float bb[4] = {b4.x, b4.y, b4.z, b4.w};
#pragma unroll
            for (int nt = 0; nt < 4; ++nt) {
                const int n = n0 + nt * 16 + lm;
                f16x4 o = {(f16)((acc[h][nt][0] + bb[0]) * sc),
                           (f16)((acc[h][nt][1] + bb[1]) * sc),
                           (f16)((acc[h][nt][2] + bb[2]) * sc),
                           (f16)((acc[h][nt][3] + bb[3]) * sc)};
                *reinterpret_cast<f16x4*>(
                    &Out[((size_t)((b * NHEADS + h) * NT + n)) * HC + c_base]) = o;
            }
        }
    } else {
        __syncthreads();   // x-tile dead; reuse SMEM as Vt[256][80]
#pragma unroll
        for (int h = 0; h < 4; ++h)
#pragma unroll
            for (int nt = 0; nt < 4; ++nt)
#pragma unroll
                for (int r = 0; r < 4; ++r)
                    Vt[h * 64 + c_base + r][nt * 16 + lm] = (f16)acc[h][nt][r];
        __syncthreads();
#pragma unroll
        for (int p = 0; p < 8; ++p) {
            const int c  = p * 32 + (t >> 3);
            const int nn = (t & 7) * 8;
            const float bb = Bi[c];
            const f16x8 vv = *reinterpret_cast<const f16x8*>(&Vt[c][nn]);
            f16x8 o;
#pragma unroll
            for (int j = 0; j < 8; ++j) o[j] = (f16)((float)vv[j] + bb);
            *reinterpret_cast<f16x8*>(
                &Vg[((size_t)((b * NHEADS + (c >> 6)) * HC + (c & 63))) * NT
                    + n0 + nn]) = o;
        }
    }
}

// ---------------------------------------------------------------------------
// Flash attention PASS 1: 256-QUERY TILES, 8-wave blocks (512 thr).
// grid 576 = (9 qt x 4 seg x 16 bh, XCD-mapped) -> 2.25 blocks/CU x 8 waves
// = 18 waves/CU (unchanged from R24/R25) at HALVED staged traffic (83 MB;
// each 16KB chunk now serves 256 queries). Staging: 2 gload_lds/wave/chunk
// (waves 0-3 K rows, waves 4-7 V rows). Per-wave inner loop = R24.
// ---------------------------------------------------------------------------
__global__ __launch_bounds__(512) void attn_p1(
    const f16* __restrict__ Kt, const f16* __restrict__ Qt,
    const f16* __restrict__ Vg,
    f16* __restrict__ Pa, float* __restrict__ Pm, float* __restrict__ Pl)
{
    __shared__ f16 SM[2][2][4096];   // [buf][K/V][64 rows x 64c], 32 KB

    const int t = threadIdx.x, l = t & 63, w = t >> 6;   // w: 0..7
    const int col = l & 31, hi = l >> 5;

    const int bid = blockIdx.x;
    const int xcd = bid & 7, idx = bid >> 3;          // 72 per XCD
    const int second = idx >= 36 ? 1 : 0;
    const int bh = 2 * xcd + second;                  // 2 (b,h) pairs per XCD
    const int idx2 = idx - 36 * second;               // 0..35
    const int qt = idx2 >> 2, seg = idx2 & 3;         // qt 0..8, seg 0..3
    const int b = bh >> 2, h = bh & 3;
    const int m0 = qt * QTILE;

    const size_t bhs = (size_t)(b * NHEADS + h);
    const f16* Kb = Kt + bhs * NT * HC;   // [n][64c]
    const f16* Qb = Qt + bhs * NT * HC;
    const f16* Vb = Vg + bhs * HC * NT;   // [c][n]

    const int srow = l >> 3, su = l & 7, sx = su ^ srow;

    const int q = m0 + w * 32 + col;
    f16x8 qf[4];
#pragma unroll
    for (int cs = 0; cs < 4; ++cs)
        qf[cs] = *reinterpret_cast<const f16x8*>(
            &Qb[(size_t)q * HC + cs * 16 + hi * 8]);

    const f32x16 Z16 = {0,0,0,0,0,0,0,0,0,0,0,0,0,0,0,0};
    f32x16 acc0 = Z16, acc1 = Z16;
    float m_run = -3.0e38f, l_run = 0.0f;

    const int kbase = seg * KSEG;

    // 8 waves: w0-3 stage K rows (w&3)*16..+16, w4-7 stage V likewise.
    // 2 gload_lds per wave per chunk.
    auto stage = [&](int kc, int buf) {
        const int rbase = (w & 3) * 16;
        if (w < 4) {
            const char* src = (const char*)(Kb + (size_t)kc * HC);
            char* dst = (char*)&SM[buf][0][0];
#pragma unroll
            for (int g = 0; g < 2; ++g) {
                const int rb = rbase + g * 8;
                gload_lds16(src + (size_t)(rb + srow) * 128 + (sx << 4),
                            dst + rb * 128);
            }
        } else {
            const char* src = (const char*)Vb + (size_t)kc * 2;
            char* dst = (char*)&SM[buf][1][0];
#pragma unroll
            for (int g = 0; g < 2; ++g) {
                const int rb = rbase + g * 8;
                gload_lds16(src + (size_t)(rb + srow) * (NT * 2) + (sx << 4),
                            dst + rb * 128);
            }
        }
    };

    auto rd = [&](const f16* base, int row, int u) -> f16x8 {
        return *reinterpret_cast<const f16x8*>(
            base + row * 64 + ((u ^ (row & 7)) << 3));
    };

    stage(kbase, 0);
    __syncthreads();

    for (int i = 0; i < NSEG; ++i) {
        const int cur = i & 1;
        if (i + 1 < NSEG) stage(kbase + (i + 1) * 64, cur ^ 1);

        const f16* Kc = &SM[cur][0][0];
        const f16* Vc = &SM[cur][1][0];

        f32x16 s0 = Z16, s1 = Z16;
#pragma unroll
        for (int cs = 0; cs < 4; ++cs) {
            const f16x8 k0 = rd(Kc, col,      cs * 2 + hi);
            const f16x8 k1 = rd(Kc, 32 + col, cs * 2 + hi);
            s0 = MFMA32(k0, qf[cs], s0);
            s1 = MFMA32(k1, qf[cs], s1);
        }

        float m8[8];
#pragma unroll
        for (int j = 0; j < 8; ++j)
            m8[j] = fmaxf(fmaxf(s0[2 * j], s0[2 * j + 1]),
                          fmaxf(s1[2 * j], s1[2 * j + 1]));
        float cm = fmaxf(fmaxf(fmaxf(m8[0], m8[1]), fmaxf(m8[2], m8[3])),
                         fmaxf(fmaxf(m8[4], m8[5]), fmaxf(m8[6], m8[7])));
        cm = fmaxf(cm, __shfl_xor(cm, 32));
        if (!__all(cm <= m_run + THR2)) {     // defer-max (log2 domain)
            const float mN = fmaxf(m_run, cm);
            const float fac = ex2(m_run - mN);
#pragma unroll
            for (int r = 0; r < 16; ++r) { acc0[r] *= fac; acc1[r] *= fac; }
            l_run *= fac;
            m_run = mN;
        }
        float p0[16], p1[16];
        float ps0 = 0.f, ps1 = 0.f, ps2 = 0.f, ps3 = 0.f;
#pragma unroll
        for (int r = 0; r < 4; ++r) {
            p0[r]      = ex2(s0[r]      - m_run); ps0 += p0[r];
            p0[r + 4]  = ex2(s0[r + 4]  - m_run); ps1 += p0[r + 4];
            p0[r + 8]  = ex2(s0[r + 8]  - m_run); ps2 += p0[r + 8];
            p0[r + 12] = ex2(s0[r + 12] - m_run); ps3 += p0[r + 12];
            p1[r]      = ex2(s1[r]      - m_run); ps0 += p1[r];
            p1[r + 4]  = ex2(s1[r + 4]  - m_run); ps1 += p1[r + 4];
            p1[r + 8]  = ex2(s1[r + 8]  - m_run); ps2 += p1[r + 8];
            p1[r + 12] = ex2(s1[r + 12] - m_run); ps3 += p1[r + 12];
        }
        l_run += (ps0 + ps1) + (ps2 + ps3);

        unsigned a0[8], a1[8];
#pragma unroll
        for (int j = 0; j < 8; ++j) {
            a0[j] = pkh(p0[2 * j], p0[2 * j + 1]);
            a1[j] = pkh(p1[2 * j], p1[2 * j + 1]);
        }
        swap32(a0[0], a0[2]); swap32(a0[1], a0[3]);
        swap32(a0[4], a0[6]); swap32(a0[5], a0[7]);
        swap32(a1[0], a1[2]); swap32(a1[1], a1[3]);
        swap32(a1[4], a1[6]); swap32(a1[5], a1[7]);
        union BU { unsigned u[4]; f16x8 v; };
        BU fr[4];
        fr[0].u[0] = a0[0]; fr[0].u[1] = a0[1]; fr[0].u[2] = a0[2]; fr[0].u[3] = a0[3];
        fr[1].u[0] = a0[4]; fr[1].u[1] = a0[5]; fr[1].u[2] = a0[6]; fr[1].u[3] = a0[7];
        fr[2].u[0] = a1[0]; fr[2].u[1] = a1[1]; fr[2].u[2] = a1[2]; fr[2].u[3] = a1[3];
        fr[3].u[0] = a1[4]; fr[3].u[1] = a1[5]; fr[3].u[2] = a1[6]; fr[3].u[3] = a1[7];

#pragma unroll
        for (int kk = 0; kk < 4; ++kk) {
            const f16x8 v0 = rd(Vc, col,      kk * 2 + hi);
            const f16x8 v1 = rd(Vc, 32 + col, kk * 2 + hi);
            acc0 = MFMA32(v0, fr[kk].v, acc0);
            acc1 = MFMA32(v1, fr[kk].v, acc1);
        }

        __syncthreads();   // publishes prefetch; frees buf for i+1's stage
    }

    // ---- publish normalized partials (m in log2 domain) -----------------
    const float l_full = l_run + __shfl_xor(l_run, 32);
    const float inv = 1.0f / l_full;
    const size_t pq = ((size_t)((seg * 16 + bh) * NQT + qt)) * QTILE + w * 32 + col;
    if (hi == 0) { Pm[pq] = m_run; Pl[pq] = l_full; }
    f16* row = Pa + pq * 64;
#pragma unroll
    for (int rq = 0; rq < 4; ++rq) {
        const int c0 = rq * 8 + hi * 4;
        f16x4 o0 = {(f16)(acc0[rq * 4 + 0] * inv), (f16)(acc0[rq * 4 + 1] * inv),
                    (f16)(acc0[rq * 4 + 2] * inv), (f16)(acc0[rq * 4 + 3] * inv)};
        f16x4 o1 = {(f16)(acc1[rq * 4 + 0] * inv), (f16)(acc1[rq * 4 + 1] * inv),
                    (f16)(acc1[rq * 4 + 2] * inv), (f16)(acc1[rq * 4 + 3] * inv)};
        *reinterpret_cast<f16x4*>(row + c0) = o0;
        *reinterpret_cast<f16x4*>(row + 32 + c0) = o1;
    }
}

// ---------------------------------------------------------------------------
// FUSED merge + final conv1x1, head-split (R25; qt decode for 256-q tiles).
// grid (36, 4, 2) = (ntile64, b, head-pair), block 256.
// ---------------------------------------------------------------------------
__global__ __launch_bounds__(256) void out_fused(
    const f16* __restrict__ wo16, const float* __restrict__ bo,
    const f16* __restrict__ Pa, const float* __restrict__ Pm,
    const float* __restrict__ Pl, float* __restrict__ Y)
{
    __shared__ f16 T[64][264];   // merged attention output tile [n][c]

    const int t = threadIdx.x, l = t & 63, w = t >> 6;
    const int lm = l & 15, lg = l >> 4;
    const int n0 = blockIdx.x * 64;
    const int b = blockIdx.y;
    const int hz = blockIdx.z;            // head-pair: o-tiles {2hz, 2hz+1}
    const int qt = n0 >> 8, ql0 = n0 & 255;

    // ---- phase 1: merge (all 4 heads) -----------------------------------
    {
        const int n = t >> 2, c16 = (t & 3) * 16;
#pragma unroll
        for (int h = 0; h < 4; ++h) {
            const int bh = b * NHEADS + h;
            size_t ix[NSEGS];
            float m[NSEGS], c[NSEGS];
            float M = -3.0e38f;
#pragma unroll
            for (int s = 0; s < NSEGS; ++s) {
                ix[s] = ((size_t)((s * 16 + bh) * NQT + qt)) * QTILE + ql0 + n;
                m[s] = Pm[ix[s]];
                M = fmaxf(M, m[s]);
            }
            float csum = 0.f;
#pragma unroll
            for (int s = 0; s < NSEGS; ++s) {
                c[s] = ex2(m[s] - M) * Pl[ix[s]];
                csum += c[s];
            }
            const float inv = 1.0f / csum;
            float v[16] = {};
#pragma unroll
            for (int s = 0; s < NSEGS; ++s) {
                const f16* r = Pa + ix[s] * 64 + c16;
                const f16x8 a0 = *reinterpret_cast<const f16x8*>(r);
                const f16x8 a1 = *reinterpret_cast<const f16x8*>(r + 8);
#pragma unroll
                for (int j = 0; j < 8; ++j) {
                    v[j]     += c[s] * (float)a0[j];
                    v[8 + j] += c[s] * (float)a1[j];
                }
            }
            f16x8 o0, o1;
#pragma unroll
            for (int j = 0; j < 8; ++j) {
                o0[j] = (f16)(v[j] * inv);
                o1[j] = (f16)(v[8 + j] * inv);
            }
            *reinterpret_cast<f16x8*>(&T[n][h * 64 + c16]) = o0;
            *reinterpret_cast<f16x8*>(&T[n][h * 64 + c16 + 8]) = o1;
        }
    }
    __syncthreads();

    // ---- phase 2: GEMM over this block's 2 o-tiles -----------------------
    f32x4 acc[2][4] = {};   // [hp][nt]
#pragma unroll 2
    for (int ks = 0; ks < 8; ++ks) {
        f16x8 bf[4];
#pragma unroll
        for (int nt = 0; nt < 4; ++nt)
            bf[nt] = *reinterpret_cast<const f16x8*>(
                &T[nt * 16 + lm][ks * 32 + lg * 8]);
#pragma unroll
        for (int hp = 0; hp < 2; ++hp) {
            const int oo = (hz * 2 + hp) * 64;
            const f16x8 a = *reinterpret_cast<const f16x8*>(
                &wo16[(size_t)(oo + w * 16 + lm) * CH + ks * 32 + lg * 8]);
#pragma unroll
            for (int nt = 0; nt < 4; ++nt)
                acc[hp][nt] = MFMA16(a, bf[nt], acc[hp][nt]);
        }
    }

    const int c_base = w * 16 + lg * 4;
#pragma unroll
    for (int hp = 0; hp < 2; ++hp) {
        const int oo = (hz * 2 + hp) * 64;
        const float4 b4 = *reinterpret_cast<const float4*>(&bo[oo + c_base]);
        const float bb[4] = {b4.x, b4.y, b4.z, b4.w};
#pragma unroll
        for (int nt = 0; nt < 4; ++nt) {
            const int n = n0 + nt * 16 + lm;
#pragma unroll
            for (int r = 0; r < 4; ++r)
                Y[((size_t)(b * CH + oo + c_base + r)) * NT + n] =
                    acc[hp][nt][r] + bb[r];
        }
    }
}

// ---------------------------------------------------------------------------
extern "C" void kernel_launch(void* const* d_in, const int* in_sizes, int n_in,
                              void* d_out, int out_size, void* d_ws, size_t ws_size,
                              hipStream_t stream) {
    (void)in_sizes; (void)n_in; (void)out_size; (void)ws_size;
    const float* x  = (const float*)d_in[0];
    const float* wk = (const float*)d_in[1];
    const float* bk = (const float*)d_in[2];
    const float* wq = (const float*)d_in[3];
    const float* bq = (const float*)d_in[4];
    const float* wv = (const float*)d_in[5];
    const float* bv = (const float*)d_in[6];
    const float* wo = (const float*)d_in[7];
    const float* bo = (const float*)d_in[8];
    float* out = (float*)d_out;

    const size_t SZ = (size_t)NB * NT * CH;           // 2,359,296 f16 per tensor
    f16* Kt  = (f16*)d_ws;                            // [b][h][n][c]
    f16* Qt  = Kt + SZ;                               // [b][h][n][c] (pre-scaled)
    f16* Vg  = Qt + SZ;                               // [b][h][c][n]
    f16* W16 = Vg + SZ;                               // [4][65536] f16
    f16* Pa  = W16 + 4 * 65536;                       // [4][16][9][256][64] f16
    float* Pm = (float*)(Pa + (size_t)NSEGS * 16 * NQT * QTILE * 64);
    float* Pl = Pm + (size_t)NSEGS * 16 * NQT * QTILE;   // total ws ~34 MB

    wcvt<<<dim3(128), 256, 0, stream>>>(wk, wq, wv, wo, W16);
    proj_qkv_v3<<<dim3(36, 3, 4), 256, 0, stream>>>(
        W16, bk, bq, bv, x, Kt, Qt, Vg);
    attn_p1<<<dim3(576), 512, 0, stream>>>(Kt, Qt, Vg, Pa, Pm, Pl);
    out_fused<<<dim3(36, 4, 2), 256, 0, stream>>>(
        W16 + 3 * 65536, bo, Pa, Pm, Pl, out);
}